// Round 5
// baseline (6131.798 us; speedup 1.0000x reference)
//
#include <hip/hip_runtime.h>
#include <hip/hip_fp16.h>

// Problem: S,B,E,H,V,O = 1024,256,128,256,32000,2
#define S_LEN 1024
#define BATCH 256
#define EDIM  128
#define HDIM  256
#define ODIM  2

typedef unsigned int uint32;
typedef _Float16 half_t;
typedef half_t half2v __attribute__((ext_vector_type(2)));
typedef half_t half8  __attribute__((ext_vector_type(8)));
typedef float  f32x4  __attribute__((ext_vector_type(4)));

// ---------------- ws layout (uint32 units) ----------------
// whhf: W_hh A-frags [4 q][4 j][4 g][8 t][64 lane][4 dw]   (f16 pairs)
// wihf: W_ih A-frags [4 q][4 j][4 g][4 t][64 lane][4 dw]
// hbuf: [2 parity][16 c][16 b][128 dw]  h as f16 pairs (u-major)
// flags:[16 c][16 wave][32]  128B-isolated monotonic counters
#define OFF_WHHF   0
#define OFF_WIHF   131072
#define OFF_HBUF   196608
#define OFF_FLAG   262144
#define N_FLAG     8192

__device__ __forceinline__ float sigf(float x)     { return 1.0f / (1.0f + __expf(-x)); }
__device__ __forceinline__ float tanhfast(float x) { return 1.0f - 2.0f / (__expf(2.0f * x) + 1.0f); }

__device__ __forceinline__ uint32 packh2(float a, float b) {
  union { uint32 u; half2v h; } c; c.h[0] = (half_t)a; c.h[1] = (half_t)b; return c.u;
}
__device__ __forceinline__ half8 as_h8(uint4 v) {
  union { uint4 u; half8 h; } c; c.u = v; return c.h;
}

#define AQ_LD(pp)      __hip_atomic_load((pp), __ATOMIC_RELAXED, __HIP_MEMORY_SCOPE_AGENT)
#define AQ_ST(pp, vv)  __hip_atomic_store((pp), (vv), __ATOMIC_RELAXED, __HIP_MEMORY_SCOPE_AGENT)

#if defined(__has_builtin)
#if __has_builtin(__builtin_amdgcn_sched_barrier)
#define SCHED_FENCE() __builtin_amdgcn_sched_barrier(0)
#endif
#endif
#ifndef SCHED_FENCE
#define SCHED_FENCE()
#endif

// ---------------- prep: pack W into per-lane MFMA A-fragment order ----------------
// A-layout (16x16x32): lane l holds A[m=l&15][k=(l>>4)*8 + 2d+{0,1}].
// Tile (q,j,g): rows = g*256 + q*64 + j*16 + [0,16); k-tile t: k += t*32.
__global__ void prep_kernel(const float* __restrict__ w_ih, const float* __restrict__ w_hh,
                            uint32* __restrict__ ws_u) {
  int id = blockIdx.x * 256 + threadIdx.x;
  if (id < 131072) {            // whhf
    int q = id >> 15, j = (id >> 13) & 3, g = (id >> 11) & 3, t = (id >> 8) & 7,
        l = (id >> 2) & 63, d = id & 3;
    int grow = g * 256 + q * 64 + j * 16 + (l & 15);
    int k = t * 32 + ((l >> 4) & 3) * 8 + 2 * d;
    ws_u[OFF_WHHF + id] = packh2(w_hh[grow * HDIM + k], w_hh[grow * HDIM + k + 1]);
  } else if (id < 196608) {     // wihf
    int i2 = id - 131072;
    int q = i2 >> 14, j = (i2 >> 12) & 3, g = (i2 >> 10) & 3, t = (i2 >> 8) & 3,
        l = (i2 >> 2) & 63, d = i2 & 3;
    int grow = g * 256 + q * 64 + j * 16 + (l & 15);
    int k = t * 32 + ((l >> 4) & 3) * 8 + 2 * d;
    ws_u[OFF_WIHF + i2] = packh2(w_ih[grow * EDIM + k], w_ih[grow * EDIM + k + 1]);
  } else if (id < 196608 + N_FLAG) {
    ((int*)(ws_u + OFF_FLAG))[id - 196608] = 0;
  }
}

// ---------------- LSTM: wave-autonomous MFMA recurrence, zero __syncthreads ----------------
// 64 blocks = 16 clusters x 4 members. Cluster c = bid&15 (batch cols 16c..16c+15),
// member q = bid>>4 (units 64q..64q+63) -> members {c,16+c,32+c,48+c} same XCD mod-8 heuristic.
// Block = 4 waves; wave j owns units q*64+j*16..+16, ALL 4 gates, ALL 16 cols:
// epilogue is lane-local (i,f,g,o land in the same lane) -> no cross-wave traffic at all.
// All weights live in VGPRs (launch_bounds(256,1): 512-VGPR budget, ~320 used, no LDS).
__global__ __launch_bounds__(256, 1) void lstm_kernel(
    const int* __restrict__ inp, const int* __restrict__ lengths,
    const float* __restrict__ h0, const float* __restrict__ c0,
    const float* __restrict__ emb,
    const float* __restrict__ b_ih, const float* __restrict__ b_hh,
    uint32* __restrict__ ws_u,
    float* __restrict__ outh, float* __restrict__ outc) {
  const int tid  = threadIdx.x;
  const int lane = tid & 63, j = tid >> 6;
  const int c = blockIdx.x & 15, q = blockIdx.x >> 4;
  const int n = lane & 15, p = (lane >> 4) & 3;   // MFMA col / quad

  const uint4* whhf4 = (const uint4*)(ws_u + OFF_WHHF);
  const uint4* wihf4 = (const uint4*)(ws_u + OFF_WIHF);
  uint32* hb = ws_u + OFF_HBUF;
  int* flags  = (int*)(ws_u + OFF_FLAG);
  int* myflag = flags + (c * 16 + q * 4 + j) * 32;

  // ---- weights -> registers (persistent A-fragments) ----
  uint4 ahh[4][8], aih[4][4];
#pragma unroll
  for (int g = 0; g < 4; ++g) {
#pragma unroll
    for (int t = 0; t < 8; ++t)
      ahh[g][t] = whhf4[(((q * 4 + j) * 4 + g) * 8 + t) * 64 + lane];
#pragma unroll
    for (int t = 0; t < 4; ++t)
      aih[g][t] = wihf4[(((q * 4 + j) * 4 + g) * 4 + t) * 64 + lane];
  }

  // ---- per-lane state: bias (acc-init), c-state, length, out base ----
  float bias_[4][4], cst[4];
  const int ob = (16 * c + n) * HDIM + q * 64 + j * 16 + p * 4;
#pragma unroll
  for (int g = 0; g < 4; ++g)
#pragma unroll
    for (int r = 0; r < 4; ++r) {
      int grow = g * 256 + q * 64 + j * 16 + p * 4 + r;
      bias_[g][r] = b_ih[grow] + b_hh[grow];
    }
#pragma unroll
  for (int r = 0; r < 4; ++r) cst[r] = c0[ob + r];
  const int len = lengths[16 * c + n] - 1;

  // ---- x_0 B-frags -> registers ----
  const float2* emb2 = (const float2*)emb;
  uint4 xcur[4];
  {
    int tok = inp[16 * c + n];
#pragma unroll
    for (int t = 0; t < 4; ++t) {
      float2 e0 = emb2[tok * 64 + t * 16 + p * 4 + 0];
      float2 e1 = emb2[tok * 64 + t * 16 + p * 4 + 1];
      float2 e2 = emb2[tok * 64 + t * 16 + p * 4 + 2];
      float2 e3 = emb2[tok * 64 + t * 16 + p * 4 + 3];
      xcur[t] = (uint4){ packh2(e0.x, e0.y), packh2(e1.x, e1.y),
                         packh2(e2.x, e2.y), packh2(e3.x, e3.y) };
    }
  }

  // ---- stage h0 slice into hbuf parity 1, then per-wave flag=1 ----
  {
    float v0 = h0[ob], v1 = h0[ob + 1], v2 = h0[ob + 2], v3 = h0[ob + 3];
    uint32 sb = ((16 + c) * 16 + n) * 128 + q * 32 + j * 8 + p * 2;
    AQ_ST(hb + sb, packh2(v0, v1));
    AQ_ST(hb + sb + 1, packh2(v2, v3));
  }
  __builtin_amdgcn_s_waitcnt(0x0F70);   // vmcnt(0) only: wave's stores at coherence point
  if (lane == 0) AQ_ST(myflag, 1);

  for (int s = 0; s < S_LEN; ++s) {
    const int par = s & 1;

    // ---- acc init = bias; x-part MFMA (independent of h: overlaps flag propagation) ----
    f32x4 acc[4];
#pragma unroll
    for (int g = 0; g < 4; ++g)
      acc[g] = (f32x4){ bias_[g][0], bias_[g][1], bias_[g][2], bias_[g][3] };
#pragma unroll
    for (int t = 0; t < 4; ++t)
#pragma unroll
      for (int g = 0; g < 4; ++g)
        acc[g] = __builtin_amdgcn_mfma_f32_16x16x32_f16(as_h8(aih[g][t]), as_h8(xcur[t]),
                                                        acc[g], 0, 0, 0);

    // ---- prefetch x_{s+1} (off critical path; waits sink to first use) ----
    uint4 xnext[4];
    {
      int snext = (s + 1 < S_LEN) ? s + 1 : s;
      int tok = inp[snext * BATCH + 16 * c + n];
#pragma unroll
      for (int t = 0; t < 4; ++t) {
        float2 e0 = emb2[tok * 64 + t * 16 + p * 4 + 0];
        float2 e1 = emb2[tok * 64 + t * 16 + p * 4 + 1];
        float2 e2 = emb2[tok * 64 + t * 16 + p * 4 + 2];
        float2 e3 = emb2[tok * 64 + t * 16 + p * 4 + 3];
        xnext[t] = (uint4){ packh2(e0.x, e0.y), packh2(e1.x, e1.y),
                            packh2(e2.x, e2.y), packh2(e3.x, e3.y) };
      }
    }

    // ---- poll all 16 producer-wave flags of this cluster (64-lane ballot) ----
    {
      const int target = s + 1;
      const int* fl = flags + (c * 16 + n) * 32;   // 4 lanes share each flag line
      for (;;) {
        int fv = AQ_LD(fl);
        if (__ballot(fv < target) == 0ull) break;
      }
    }
    SCHED_FENCE();   // keep h loads below the poll exit

    // ---- h_{s-1} B-frags: global -> VGPR (L1-bypass relaxed agent loads) ----
    uint4 hbv[8];
    {
      const uint32* lb = hb + (((par ^ 1) * 16 + c) * 16 + n) * 128 + p * 4;
#pragma unroll
      for (int t = 0; t < 8; ++t) {
        hbv[t].x = AQ_LD(lb + t * 16 + 0);
        hbv[t].y = AQ_LD(lb + t * 16 + 1);
        hbv[t].z = AQ_LD(lb + t * 16 + 2);
        hbv[t].w = AQ_LD(lb + t * 16 + 3);
      }
    }

    // ---- h-part MFMA ----
#pragma unroll
    for (int t = 0; t < 8; ++t)
#pragma unroll
      for (int g = 0; g < 4; ++g)
        acc[g] = __builtin_amdgcn_mfma_f32_16x16x32_f16(as_h8(ahh[g][t]), as_h8(hbv[t]),
                                                        acc[g], 0, 0, 0);

    // ---- lane-local epilogue: gates i,f,g,o all in this lane (D row = p*4+r, col = n) ----
    float hv[4];
#pragma unroll
    for (int r = 0; r < 4; ++r) {
      float iv = sigf(acc[0][r]);
      float fv = sigf(acc[1][r]);
      float gv = tanhfast(acc[2][r]);
      float ov = sigf(acc[3][r]);
      float cn = fv * cst[r] + iv * gv;
      cst[r] = cn;
      float hn = ov * tanhfast(cn);
      hv[r] = hn;
      if (s == len) { outh[ob + r] = hn; outc[ob + r] = cn; }
    }
    {
      uint32 sb = ((par * 16 + c) * 16 + n) * 128 + q * 32 + j * 8 + p * 2;
      AQ_ST(hb + sb, packh2(hv[0], hv[1]));
      AQ_ST(hb + sb + 1, packh2(hv[2], hv[3]));
    }

    // ---- per-wave publish: drain this wave's vm ops, then flag (R3/R4 protocol, wave-scope) ----
    __builtin_amdgcn_s_waitcnt(0x0F70);
    if (lane == 0) AQ_ST(myflag, s + 2);

#pragma unroll
    for (int t = 0; t < 4; ++t) xcur[t] = xnext[t];
  }
}

// ---------------- decode: [B,2] = sigmoid(last_h @ dec_w^T) ----------------
__global__ __launch_bounds__(64) void decode_kernel(const float* __restrict__ outh,
                                                    const float* __restrict__ dec_w,
                                                    float* __restrict__ dec) {
  int b = blockIdx.x, l = threadIdx.x;
  float p0 = 0.f, p1 = 0.f;
#pragma unroll
  for (int m = 0; m < HDIM / 64; ++m) {
    float h = outh[b * HDIM + l + 64 * m];
    p0 = fmaf(h, dec_w[l + 64 * m], p0);
    p1 = fmaf(h, dec_w[HDIM + l + 64 * m], p1);
  }
#pragma unroll
  for (int off = 32; off > 0; off >>= 1) {
    p0 += __shfl_down(p0, off);
    p1 += __shfl_down(p1, off);
  }
  if (l == 0) {
    dec[b * ODIM + 0] = sigf(p0);
    dec[b * ODIM + 1] = sigf(p1);
  }
}

extern "C" void kernel_launch(void* const* d_in, const int* in_sizes, int n_in,
                              void* d_out, int out_size, void* d_ws, size_t ws_size,
                              hipStream_t stream) {
  const int*   inp     = (const int*)d_in[0];
  const int*   lengths = (const int*)d_in[1];
  const float* h0      = (const float*)d_in[2];
  const float* c0      = (const float*)d_in[3];
  const float* emb     = (const float*)d_in[4];
  const float* w_ih    = (const float*)d_in[5];
  const float* w_hh    = (const float*)d_in[6];
  const float* b_ih    = (const float*)d_in[7];
  const float* b_hh    = (const float*)d_in[8];
  const float* dec_w   = (const float*)d_in[9];

  uint32* ws_u = (uint32*)d_ws;

  float* dec  = (float*)d_out;           // [B, 2]
  float* outh = dec + BATCH * ODIM;      // [1, B, H]
  float* outc = outh + BATCH * HDIM;     // [1, B, H]

  const int prep_total = 196608 + N_FLAG;
  prep_kernel<<<(prep_total + 255) / 256, 256, 0, stream>>>(w_ih, w_hh, ws_u);
  lstm_kernel<<<64, 256, 0, stream>>>(inp, lengths, h0, c0, emb, b_ih, b_hh,
                                      ws_u, outh, outc);
  decode_kernel<<<BATCH, 64, 0, stream>>>(outh, dec_w, dec);
}

// Round 6
// 5740.288 us; speedup vs baseline: 1.0682x; 1.0682x over previous
//
#include <hip/hip_runtime.h>
#include <hip/hip_fp16.h>

// Problem: S,B,E,H,V,O = 1024,256,128,256,32000,2
#define S_LEN 1024
#define BATCH 256
#define EDIM  128
#define HDIM  256
#define ODIM  2

typedef unsigned int uint32;
typedef _Float16 half_t;
typedef half_t half2v __attribute__((ext_vector_type(2)));
typedef half_t half8  __attribute__((ext_vector_type(8)));
typedef float  f32x4  __attribute__((ext_vector_type(4)));

// ---------------- ws layout (uint32 units) ----------------
// whhf: W_hh A-frags [4 q][4 j][4 g][8 t][64 lane][4 dw]   (f16 pairs)
// wihf: W_ih A-frags [4 q][4 j][4 g][4 t][64 lane][4 dw]
// hbuf: [2 parity][16 c][16 b][128 dw]  h as f16 pairs (u-major)
// flags:[16 c][16 wave][32]  128B-isolated monotonic counters
#define OFF_WHHF   0
#define OFF_WIHF   131072
#define OFF_HBUF   196608
#define OFF_FLAG   262144
#define N_FLAG     8192

__device__ __forceinline__ float sigf(float x)     { return 1.0f / (1.0f + __expf(-x)); }
__device__ __forceinline__ float tanhfast(float x) { return 1.0f - 2.0f / (__expf(2.0f * x) + 1.0f); }

__device__ __forceinline__ uint32 packh2(float a, float b) {
  union { uint32 u; half2v h; } c; c.h[0] = (half_t)a; c.h[1] = (half_t)b; return c.u;
}
__device__ __forceinline__ half8 as_h8(uint4 v) {
  union { uint4 u; half8 h; } c; c.u = v; return c.h;
}

// Agent-scope relaxed atomic LOAD (sc0: L1-bypass, L2-snooping) — R3/R4-proven consumer side.
#define AQ_LD(pp)      __hip_atomic_load((pp), __ATOMIC_RELAXED, __HIP_MEMORY_SCOPE_AGENT)
// Agent-scope store ONLY for flags (write-through; tiny traffic).
#define AQ_ST(pp, vv)  __hip_atomic_store((pp), (vv), __ATOMIC_RELAXED, __HIP_MEMORY_SCOPE_AGENT)
// Workgroup-scope atomic store: emits a PLAIN write-back global_store (stays in XCD L2,
// consumer-visible there — exactly R3/R4's plain-store protocol, minus the 268 MB
// write-through storm R5's agent-scope data stores caused).
#define WB_ST(pp, vv)  __hip_atomic_store((pp), (vv), __ATOMIC_RELAXED, __HIP_MEMORY_SCOPE_WORKGROUP)

#if defined(__has_builtin)
#if __has_builtin(__builtin_amdgcn_sched_barrier)
#define SCHED_FENCE() __builtin_amdgcn_sched_barrier(0)
#endif
#endif
#ifndef SCHED_FENCE
#define SCHED_FENCE()
#endif

// ---------------- prep: pack W into per-lane MFMA A-fragment order ----------------
// A-layout (16x16x32): lane l holds A[m=l&15][k=(l>>4)*8 + 2d+{0,1}].
// Tile (q,j,g): rows = g*256 + q*64 + j*16 + [0,16); k-tile t: k += t*32.
__global__ void prep_kernel(const float* __restrict__ w_ih, const float* __restrict__ w_hh,
                            uint32* __restrict__ ws_u) {
  int id = blockIdx.x * 256 + threadIdx.x;
  if (id < 131072) {            // whhf
    int q = id >> 15, j = (id >> 13) & 3, g = (id >> 11) & 3, t = (id >> 8) & 7,
        l = (id >> 2) & 63, d = id & 3;
    int grow = g * 256 + q * 64 + j * 16 + (l & 15);
    int k = t * 32 + ((l >> 4) & 3) * 8 + 2 * d;
    ws_u[OFF_WHHF + id] = packh2(w_hh[grow * HDIM + k], w_hh[grow * HDIM + k + 1]);
  } else if (id < 196608) {     // wihf
    int i2 = id - 131072;
    int q = i2 >> 14, j = (i2 >> 12) & 3, g = (i2 >> 10) & 3, t = (i2 >> 8) & 3,
        l = (i2 >> 2) & 63, d = i2 & 3;
    int grow = g * 256 + q * 64 + j * 16 + (l & 15);
    int k = t * 32 + ((l >> 4) & 3) * 8 + 2 * d;
    ws_u[OFF_WIHF + i2] = packh2(w_ih[grow * EDIM + k], w_ih[grow * EDIM + k + 1]);
  } else if (id < 196608 + N_FLAG) {
    ((int*)(ws_u + OFF_FLAG))[id - 196608] = 0;
  }
}

// ---------------- LSTM: wave-autonomous MFMA recurrence, zero __syncthreads ----------------
// 64 blocks = 16 clusters x 4 members. Cluster c = bid&15 (batch cols 16c..16c+15),
// member q = bid>>4 (units 64q..64q+63) -> members {c,16+c,32+c,48+c} same XCD mod-8
// heuristic (empirically held R3-R5; consumers read producer data through the shared XCD L2).
// Block = 4 waves; wave j owns units q*64+j*16..+16, ALL 4 gates, ALL 16 cols:
// epilogue fully lane-local. All weights live in registers.
__global__ __launch_bounds__(256, 1) void lstm_kernel(
    const int* __restrict__ inp, const int* __restrict__ lengths,
    const float* __restrict__ h0, const float* __restrict__ c0,
    const float* __restrict__ emb,
    const float* __restrict__ b_ih, const float* __restrict__ b_hh,
    uint32* __restrict__ ws_u,
    float* __restrict__ outh, float* __restrict__ outc) {
  const int tid  = threadIdx.x;
  const int lane = tid & 63, j = tid >> 6;
  const int c = blockIdx.x & 15, q = blockIdx.x >> 4;
  const int n = lane & 15, p = (lane >> 4) & 3;   // MFMA col / quad

  const uint4* whhf4 = (const uint4*)(ws_u + OFF_WHHF);
  const uint4* wihf4 = (const uint4*)(ws_u + OFF_WIHF);
  uint32* hb = ws_u + OFF_HBUF;
  int* flags  = (int*)(ws_u + OFF_FLAG);
  int* myflag = flags + (c * 16 + q * 4 + j) * 32;

  // ---- weights -> registers (persistent A-fragments) ----
  uint4 ahh[4][8], aih[4][4];
#pragma unroll
  for (int g = 0; g < 4; ++g) {
#pragma unroll
    for (int t = 0; t < 8; ++t)
      ahh[g][t] = whhf4[(((q * 4 + j) * 4 + g) * 8 + t) * 64 + lane];
#pragma unroll
    for (int t = 0; t < 4; ++t)
      aih[g][t] = wihf4[(((q * 4 + j) * 4 + g) * 4 + t) * 64 + lane];
  }

  // ---- per-lane state ----
  float bias_[4][4], cst[4];
  const int ob = (16 * c + n) * HDIM + q * 64 + j * 16 + p * 4;
#pragma unroll
  for (int g = 0; g < 4; ++g)
#pragma unroll
    for (int r = 0; r < 4; ++r) {
      int grow = g * 256 + q * 64 + j * 16 + p * 4 + r;
      bias_[g][r] = b_ih[grow] + b_hh[grow];
    }
#pragma unroll
  for (int r = 0; r < 4; ++r) cst[r] = c0[ob + r];
  const int len = lengths[16 * c + n] - 1;

  // ---- x_0 B-frags -> registers ----
  const float2* emb2 = (const float2*)emb;
  uint4 xcur[4];
  {
    int tok = inp[16 * c + n];
#pragma unroll
    for (int t = 0; t < 4; ++t) {
      float2 e0 = emb2[tok * 64 + t * 16 + p * 4 + 0];
      float2 e1 = emb2[tok * 64 + t * 16 + p * 4 + 1];
      float2 e2 = emb2[tok * 64 + t * 16 + p * 4 + 2];
      float2 e3 = emb2[tok * 64 + t * 16 + p * 4 + 3];
      xcur[t] = (uint4){ packh2(e0.x, e0.y), packh2(e1.x, e1.y),
                         packh2(e2.x, e2.y), packh2(e3.x, e3.y) };
    }
  }

  // ---- stage h0 slice into hbuf parity 1 (plain write-back), then flag=1 ----
  {
    float v0 = h0[ob], v1 = h0[ob + 1], v2 = h0[ob + 2], v3 = h0[ob + 3];
    uint32 sb = ((16 + c) * 16 + n) * 128 + q * 32 + j * 8 + p * 2;
    WB_ST(hb + sb, packh2(v0, v1));
    WB_ST(hb + sb + 1, packh2(v2, v3));
  }
  __atomic_signal_fence(__ATOMIC_SEQ_CST);
  __builtin_amdgcn_s_waitcnt(0x0F70);   // vmcnt(0): this wave's stores at the L2
  if (lane == 0) AQ_ST(myflag, 1);

  for (int s = 0; s < S_LEN; ++s) {
    const int par = s & 1;

    // ---- acc init = bias; x-part MFMA (xcur prefetched last step; overlaps flag propagation) ----
    f32x4 acc[4];
#pragma unroll
    for (int g = 0; g < 4; ++g)
      acc[g] = (f32x4){ bias_[g][0], bias_[g][1], bias_[g][2], bias_[g][3] };
#pragma unroll
    for (int t = 0; t < 4; ++t)
#pragma unroll
      for (int g = 0; g < 4; ++g)
        acc[g] = __builtin_amdgcn_mfma_f32_16x16x32_f16(as_h8(aih[g][t]), as_h8(xcur[t]),
                                                        acc[g], 0, 0, 0);

    // ---- poll cluster's 16 producer-wave flags: 16 active lanes only ----
    {
      const int target = s + 1;
      if (lane < 16) {
        const int* fl = flags + (c * 16 + lane) * 32;
        for (;;) {
          int fv = AQ_LD(fl);
          if (__ballot(fv < target) == 0ull) break;   // ballot over the 16 active lanes
        }
      }
    }
    SCHED_FENCE();   // keep h loads below the poll exit

    // ---- h_{s-1} B-frags: global -> VGPR (agent atomic dword loads; L2 hits) ----
    uint4 hbv[8];
    {
      const uint32* lb = hb + (((par ^ 1) * 16 + c) * 16 + n) * 128 + p * 4;
#pragma unroll
      for (int t = 0; t < 8; ++t) {
        hbv[t].x = AQ_LD(lb + t * 16 + 0);
        hbv[t].y = AQ_LD(lb + t * 16 + 1);
        hbv[t].z = AQ_LD(lb + t * 16 + 2);
        hbv[t].w = AQ_LD(lb + t * 16 + 3);
      }
    }

    // ---- h-part MFMA ----
#pragma unroll
    for (int t = 0; t < 8; ++t)
#pragma unroll
      for (int g = 0; g < 4; ++g)
        acc[g] = __builtin_amdgcn_mfma_f32_16x16x32_f16(as_h8(ahh[g][t]), as_h8(hbv[t]),
                                                        acc[g], 0, 0, 0);

    // ---- lane-local epilogue (D row = p*4+r, col = n) ----
    float hv[4];
#pragma unroll
    for (int r = 0; r < 4; ++r) {
      float iv = sigf(acc[0][r]);
      float fv = sigf(acc[1][r]);
      float gv = tanhfast(acc[2][r]);
      float ov = sigf(acc[3][r]);
      float cn = fv * cst[r] + iv * gv;
      cst[r] = cn;
      float hn = ov * tanhfast(cn);
      hv[r] = hn;
      if (s == len) { outh[ob + r] = hn; outc[ob + r] = cn; }
    }
    {
      uint32 sb = ((par * 16 + c) * 16 + n) * 128 + q * 32 + j * 8 + p * 2;
      WB_ST(hb + sb, packh2(hv[0], hv[1]));
      WB_ST(hb + sb + 1, packh2(hv[2], hv[3]));
    }

    // ---- publish: drain THIS wave's vm ops (local-L2 acks only — x-prefetch not yet
    // issued, h stores are write-back), then flag. ----
    __atomic_signal_fence(__ATOMIC_SEQ_CST);
    __builtin_amdgcn_s_waitcnt(0x0F70);
    if (lane == 0) AQ_ST(myflag, s + 2);

    // ---- NOW prefetch x_{s+1} (emb HBM-miss latency overlaps next poll window) ----
    {
      int snext = (s + 1 < S_LEN) ? s + 1 : s;
      int tok = inp[snext * BATCH + 16 * c + n];
#pragma unroll
      for (int t = 0; t < 4; ++t) {
        float2 e0 = emb2[tok * 64 + t * 16 + p * 4 + 0];
        float2 e1 = emb2[tok * 64 + t * 16 + p * 4 + 1];
        float2 e2 = emb2[tok * 64 + t * 16 + p * 4 + 2];
        float2 e3 = emb2[tok * 64 + t * 16 + p * 4 + 3];
        xcur[t] = (uint4){ packh2(e0.x, e0.y), packh2(e1.x, e1.y),
                           packh2(e2.x, e2.y), packh2(e3.x, e3.y) };
      }
    }
  }
}

// ---------------- decode: [B,2] = sigmoid(last_h @ dec_w^T) ----------------
__global__ __launch_bounds__(64) void decode_kernel(const float* __restrict__ outh,
                                                    const float* __restrict__ dec_w,
                                                    float* __restrict__ dec) {
  int b = blockIdx.x, l = threadIdx.x;
  float p0 = 0.f, p1 = 0.f;
#pragma unroll
  for (int m = 0; m < HDIM / 64; ++m) {
    float h = outh[b * HDIM + l + 64 * m];
    p0 = fmaf(h, dec_w[l + 64 * m], p0);
    p1 = fmaf(h, dec_w[HDIM + l + 64 * m], p1);
  }
#pragma unroll
  for (int off = 32; off > 0; off >>= 1) {
    p0 += __shfl_down(p0, off);
    p1 += __shfl_down(p1, off);
  }
  if (l == 0) {
    dec[b * ODIM + 0] = sigf(p0);
    dec[b * ODIM + 1] = sigf(p1);
  }
}

extern "C" void kernel_launch(void* const* d_in, const int* in_sizes, int n_in,
                              void* d_out, int out_size, void* d_ws, size_t ws_size,
                              hipStream_t stream) {
  const int*   inp     = (const int*)d_in[0];
  const int*   lengths = (const int*)d_in[1];
  const float* h0      = (const float*)d_in[2];
  const float* c0      = (const float*)d_in[3];
  const float* emb     = (const float*)d_in[4];
  const float* w_ih    = (const float*)d_in[5];
  const float* w_hh    = (const float*)d_in[6];
  const float* b_ih    = (const float*)d_in[7];
  const float* b_hh    = (const float*)d_in[8];
  const float* dec_w   = (const float*)d_in[9];

  uint32* ws_u = (uint32*)d_ws;

  float* dec  = (float*)d_out;           // [B, 2]
  float* outh = dec + BATCH * ODIM;      // [1, B, H]
  float* outc = outh + BATCH * HDIM;     // [1, B, H]

  const int prep_total = 196608 + N_FLAG;
  prep_kernel<<<(prep_total + 255) / 256, 256, 0, stream>>>(w_ih, w_hh, ws_u);
  lstm_kernel<<<64, 256, 0, stream>>>(inp, lengths, h0, c0, emb, b_ih, b_hh,
                                      ws_u, outh, outc);
  decode_kernel<<<BATCH, 64, 0, stream>>>(outh, dec_w, dec);
}

// Round 8
// 3478.500 us; speedup vs baseline: 1.7628x; 1.6502x over previous
//
#include <hip/hip_runtime.h>
#include <hip/hip_fp16.h>

// Problem: S,B,E,H,V,O = 1024,256,128,256,32000,2
#define S_LEN 1024
#define BATCH 256
#define EDIM  128
#define HDIM  256
#define ODIM  2

typedef unsigned int uint32;
typedef _Float16 half_t;
typedef half_t half2v __attribute__((ext_vector_type(2)));
typedef half_t half8  __attribute__((ext_vector_type(8)));
typedef float  f32x4  __attribute__((ext_vector_type(4)));
typedef uint32 u32x4  __attribute__((ext_vector_type(4)));

// ---------------- ws layout (uint32 units) ----------------
// whhf: W_hh A-frags [4 q][4 j][4 g][8 t][64 lane][4 dw]   (f16 pairs)
// wihf: W_ih A-frags [4 q][4 j][4 g][4 t][64 lane][4 dw]
// hbuf: [2 parity][16 c][16 b][128 dw]  h as f16 pairs (u-major)
// flags:[16 c][16 wave][32]  128B-isolated monotonic counters
#define OFF_WHHF   0
#define OFF_WIHF   131072
#define OFF_HBUF   196608
#define OFF_FLAG   262144
#define N_FLAG     8192

__device__ __forceinline__ float sigf(float x)     { return 1.0f / (1.0f + __expf(-x)); }
__device__ __forceinline__ float tanhfast(float x) { return 1.0f - 2.0f / (__expf(2.0f * x) + 1.0f); }

__device__ __forceinline__ uint32 packh2(float a, float b) {
  union { uint32 u; half2v h; } c; c.h[0] = (half_t)a; c.h[1] = (half_t)b; return c.u;
}
__device__ __forceinline__ half8 as_h8(u32x4 v) {
  union { u32x4 u; half8 h; } c; c.u = v; return c.h;
}

// ---- R3-R6 proven flag protocol: agent-scope atomic store / load ----
#define AQ_LD(pp)      __hip_atomic_load((pp), __ATOMIC_RELAXED, __HIP_MEMORY_SCOPE_AGENT)
#define AQ_ST(pp, vv)  __hip_atomic_store((pp), (vv), __ATOMIC_RELAXED, __HIP_MEMORY_SCOPE_AGENT)
// Plain write-back store for h data (stays in XCD L2; R6-proven, WRITE_SIZE ~9 MB).
#define WB_ST(pp, vv)  __hip_atomic_store((pp), (vv), __ATOMIC_RELAXED, __HIP_MEMORY_SCOPE_WORKGROUP)

// 8x global_load_dwordx4 sc0 (L1-bypass), pipelined, ONE vmcnt(0).
// "=&v" early-clobber: outputs must NOT overlap the address pair %8 (R7's crash:
// plain "=v" let load #1 clobber the pointer before loads 2-8 issued).
__device__ __forceinline__ void ld_h_frags(const uint32* lb, u32x4* hv) {
  asm volatile(
      "global_load_dwordx4 %0, %8, off sc0\n\t"
      "global_load_dwordx4 %1, %8, off offset:64 sc0\n\t"
      "global_load_dwordx4 %2, %8, off offset:128 sc0\n\t"
      "global_load_dwordx4 %3, %8, off offset:192 sc0\n\t"
      "global_load_dwordx4 %4, %8, off offset:256 sc0\n\t"
      "global_load_dwordx4 %5, %8, off offset:320 sc0\n\t"
      "global_load_dwordx4 %6, %8, off offset:384 sc0\n\t"
      "global_load_dwordx4 %7, %8, off offset:448 sc0\n\t"
      "s_waitcnt vmcnt(0)"
      : "=&v"(hv[0]), "=&v"(hv[1]), "=&v"(hv[2]), "=&v"(hv[3]),
        "=&v"(hv[4]), "=&v"(hv[5]), "=&v"(hv[6]), "=&v"(hv[7])
      : "v"(lb)
      : "memory");
}

// Drain this wave's outstanding vmem (stores acked at L2) — compiler barrier too.
#define DRAIN_VM() asm volatile("s_waitcnt vmcnt(0)" ::: "memory")

#if defined(__has_builtin)
#if __has_builtin(__builtin_amdgcn_sched_barrier)
#define SCHED_FENCE() __builtin_amdgcn_sched_barrier(0)
#endif
#endif
#ifndef SCHED_FENCE
#define SCHED_FENCE()
#endif

// ---------------- prep: pack W into per-lane MFMA A-fragment order ----------------
// A-layout (16x16x32): lane l holds A[m=l&15][k=(l>>4)*8 + 2d+{0,1}].
// Tile (q,j,g): rows = g*256 + q*64 + j*16 + [0,16); k-tile t: k += t*32.
__global__ void prep_kernel(const float* __restrict__ w_ih, const float* __restrict__ w_hh,
                            uint32* __restrict__ ws_u) {
  int id = blockIdx.x * 256 + threadIdx.x;
  if (id < 131072) {            // whhf
    int q = id >> 15, j = (id >> 13) & 3, g = (id >> 11) & 3, t = (id >> 8) & 7,
        l = (id >> 2) & 63, d = id & 3;
    int grow = g * 256 + q * 64 + j * 16 + (l & 15);
    int k = t * 32 + ((l >> 4) & 3) * 8 + 2 * d;
    ws_u[OFF_WHHF + id] = packh2(w_hh[grow * HDIM + k], w_hh[grow * HDIM + k + 1]);
  } else if (id < 196608) {     // wihf
    int i2 = id - 131072;
    int q = i2 >> 14, j = (i2 >> 12) & 3, g = (i2 >> 10) & 3, t = (i2 >> 8) & 3,
        l = (i2 >> 2) & 63, d = i2 & 3;
    int grow = g * 256 + q * 64 + j * 16 + (l & 15);
    int k = t * 32 + ((l >> 4) & 3) * 8 + 2 * d;
    ws_u[OFF_WIHF + i2] = packh2(w_ih[grow * EDIM + k], w_ih[grow * EDIM + k + 1]);
  } else if (id < 196608 + N_FLAG) {
    ((int*)(ws_u + OFF_FLAG))[id - 196608] = 0;
  }
}

// ---------------- LSTM: wave-autonomous MFMA recurrence, zero __syncthreads ----------------
// 64 blocks = 16 clusters x 4 members. Cluster c = bid&15 (batch cols 16c..16c+15),
// member q = bid>>4 (units 64q..64q+63) -> members {c,16+c,32+c,48+c} same XCD under
// round-robin dispatch (held R3-R6; data protocol validated at f16-rounding absmax).
// Block = 4 waves; wave j owns units q*64+j*16..+16, ALL 4 gates, ALL 16 cols:
// epilogue fully lane-local. All weights live in registers.
__global__ __launch_bounds__(256, 1) void lstm_kernel(
    const int* __restrict__ inp, const int* __restrict__ lengths,
    const float* __restrict__ h0, const float* __restrict__ c0,
    const float* __restrict__ emb,
    const float* __restrict__ b_ih, const float* __restrict__ b_hh,
    uint32* __restrict__ ws_u,
    float* __restrict__ outh, float* __restrict__ outc) {
  const int tid  = threadIdx.x;
  const int lane = tid & 63, j = tid >> 6;
  const int c = blockIdx.x & 15, q = blockIdx.x >> 4;
  const int n = lane & 15, p = (lane >> 4) & 3;   // MFMA col / quad

  const u32x4* whhf4 = (const u32x4*)(ws_u + OFF_WHHF);
  const u32x4* wihf4 = (const u32x4*)(ws_u + OFF_WIHF);
  uint32* hb = ws_u + OFF_HBUF;
  int* flags  = (int*)(ws_u + OFF_FLAG);
  int* myflag = flags + (c * 16 + q * 4 + j) * 32;

  // ---- weights -> registers (persistent A-fragments) ----
  u32x4 ahh[4][8], aih[4][4];
#pragma unroll
  for (int g = 0; g < 4; ++g) {
#pragma unroll
    for (int t = 0; t < 8; ++t)
      ahh[g][t] = whhf4[(((q * 4 + j) * 4 + g) * 8 + t) * 64 + lane];
#pragma unroll
    for (int t = 0; t < 4; ++t)
      aih[g][t] = wihf4[(((q * 4 + j) * 4 + g) * 4 + t) * 64 + lane];
  }

  // ---- per-lane state ----
  float bias_[4][4], cst[4];
  const int ob = (16 * c + n) * HDIM + q * 64 + j * 16 + p * 4;
#pragma unroll
  for (int g = 0; g < 4; ++g)
#pragma unroll
    for (int r = 0; r < 4; ++r) {
      int grow = g * 256 + q * 64 + j * 16 + p * 4 + r;
      bias_[g][r] = b_ih[grow] + b_hh[grow];
    }
#pragma unroll
  for (int r = 0; r < 4; ++r) cst[r] = c0[ob + r];
  const int len = lengths[16 * c + n] - 1;

  // ---- x_0 B-frags -> registers ----
  const float2* emb2 = (const float2*)emb;
  uint4 xcur[4];
  {
    int tok = inp[16 * c + n];
#pragma unroll
    for (int t = 0; t < 4; ++t) {
      float2 e0 = emb2[tok * 64 + t * 16 + p * 4 + 0];
      float2 e1 = emb2[tok * 64 + t * 16 + p * 4 + 1];
      float2 e2 = emb2[tok * 64 + t * 16 + p * 4 + 2];
      float2 e3 = emb2[tok * 64 + t * 16 + p * 4 + 3];
      xcur[t] = (uint4){ packh2(e0.x, e0.y), packh2(e1.x, e1.y),
                         packh2(e2.x, e2.y), packh2(e3.x, e3.y) };
    }
  }

  // ---- stage h0 slice into hbuf parity 1 (write-back), drain, agent flag=1 ----
  {
    float v0 = h0[ob], v1 = h0[ob + 1], v2 = h0[ob + 2], v3 = h0[ob + 3];
    uint32 sb = ((16 + c) * 16 + n) * 128 + q * 32 + j * 8 + p * 2;
    WB_ST(hb + sb, packh2(v0, v1));
    WB_ST(hb + sb + 1, packh2(v2, v3));
  }
  DRAIN_VM();
  if (lane == 0) AQ_ST(myflag, 1);

  for (int s = 0; s < S_LEN; ++s) {
    const int par = s & 1;

    // ---- acc init = bias; x-part MFMA (xcur prefetched; overlaps flag propagation) ----
    f32x4 acc[4];
#pragma unroll
    for (int g = 0; g < 4; ++g)
      acc[g] = (f32x4){ bias_[g][0], bias_[g][1], bias_[g][2], bias_[g][3] };
#pragma unroll
    for (int t = 0; t < 4; ++t) {
      union { uint4 u; u32x4 v; } xc; xc.u = xcur[t];
#pragma unroll
      for (int g = 0; g < 4; ++g)
        acc[g] = __builtin_amdgcn_mfma_f32_16x16x32_f16(as_h8(aih[g][t]), as_h8(xc.v),
                                                        acc[g], 0, 0, 0);
    }

    // ---- poll cluster's 16 producer-wave flags (16 active lanes; R6-proven) ----
    {
      const int target = s + 1;
      if (lane < 16) {
        const int* fl = flags + (c * 16 + lane) * 32;
        for (;;) {
          int fv = AQ_LD(fl);
          if (__ballot(fv < target) == 0ull) break;   // ballot over the 16 active lanes
        }
      }
    }
    SCHED_FENCE();   // keep h loads below the poll exit

    // ---- h_{s-1} B-frags: 8x dwordx4 sc0, pipelined, one vmcnt (the R8 change) ----
    u32x4 hbv[8];
    ld_h_frags(hb + (((par ^ 1) * 16 + c) * 16 + n) * 128 + p * 4, hbv);

    // ---- h-part MFMA ----
#pragma unroll
    for (int t = 0; t < 8; ++t)
#pragma unroll
      for (int g = 0; g < 4; ++g)
        acc[g] = __builtin_amdgcn_mfma_f32_16x16x32_f16(as_h8(ahh[g][t]), as_h8(hbv[t]),
                                                        acc[g], 0, 0, 0);

    // ---- lane-local epilogue (D row = p*4+r, col = n) ----
    float hv[4];
#pragma unroll
    for (int r = 0; r < 4; ++r) {
      float iv = sigf(acc[0][r]);
      float fv = sigf(acc[1][r]);
      float gv = tanhfast(acc[2][r]);
      float ov = sigf(acc[3][r]);
      float cn = fv * cst[r] + iv * gv;
      cst[r] = cn;
      float hn = ov * tanhfast(cn);
      hv[r] = hn;
      if (s == len) { outh[ob + r] = hn; outc[ob + r] = cn; }
    }
    {
      uint32 sb = ((par * 16 + c) * 16 + n) * 128 + q * 32 + j * 8 + p * 2;
      WB_ST(hb + sb, packh2(hv[0], hv[1]));
      WB_ST(hb + sb + 1, packh2(hv[2], hv[3]));
    }

    // ---- publish: drain this wave's stores (L2 ack), then agent-scope flag ----
    DRAIN_VM();
    if (lane == 0) AQ_ST(myflag, s + 2);

    // ---- prefetch x_{s+1} AFTER publish (emb miss latency overlaps next poll) ----
    {
      int snext = (s + 1 < S_LEN) ? s + 1 : s;
      int tok = inp[snext * BATCH + 16 * c + n];
#pragma unroll
      for (int t = 0; t < 4; ++t) {
        float2 e0 = emb2[tok * 64 + t * 16 + p * 4 + 0];
        float2 e1 = emb2[tok * 64 + t * 16 + p * 4 + 1];
        float2 e2 = emb2[tok * 64 + t * 16 + p * 4 + 2];
        float2 e3 = emb2[tok * 64 + t * 16 + p * 4 + 3];
        xcur[t] = (uint4){ packh2(e0.x, e0.y), packh2(e1.x, e1.y),
                           packh2(e2.x, e2.y), packh2(e3.x, e3.y) };
      }
    }
  }
}

// ---------------- decode: [B,2] = sigmoid(last_h @ dec_w^T) ----------------
__global__ __launch_bounds__(64) void decode_kernel(const float* __restrict__ outh,
                                                    const float* __restrict__ dec_w,
                                                    float* __restrict__ dec) {
  int b = blockIdx.x, l = threadIdx.x;
  float p0 = 0.f, p1 = 0.f;
#pragma unroll
  for (int m = 0; m < HDIM / 64; ++m) {
    float h = outh[b * HDIM + l + 64 * m];
    p0 = fmaf(h, dec_w[l + 64 * m], p0);
    p1 = fmaf(h, dec_w[HDIM + l + 64 * m], p1);
  }
#pragma unroll
  for (int off = 32; off > 0; off >>= 1) {
    p0 += __shfl_down(p0, off);
    p1 += __shfl_down(p1, off);
  }
  if (l == 0) {
    dec[b * ODIM + 0] = sigf(p0);
    dec[b * ODIM + 1] = sigf(p1);
  }
}

extern "C" void kernel_launch(void* const* d_in, const int* in_sizes, int n_in,
                              void* d_out, int out_size, void* d_ws, size_t ws_size,
                              hipStream_t stream) {
  const int*   inp     = (const int*)d_in[0];
  const int*   lengths = (const int*)d_in[1];
  const float* h0      = (const float*)d_in[2];
  const float* c0      = (const float*)d_in[3];
  const float* emb     = (const float*)d_in[4];
  const float* w_ih    = (const float*)d_in[5];
  const float* w_hh    = (const float*)d_in[6];
  const float* b_ih    = (const float*)d_in[7];
  const float* b_hh    = (const float*)d_in[8];
  const float* dec_w   = (const float*)d_in[9];

  uint32* ws_u = (uint32*)d_ws;

  float* dec  = (float*)d_out;           // [B, 2]
  float* outh = dec + BATCH * ODIM;      // [1, B, H]
  float* outc = outh + BATCH * HDIM;     // [1, B, H]

  const int prep_total = 196608 + N_FLAG;
  prep_kernel<<<(prep_total + 255) / 256, 256, 0, stream>>>(w_ih, w_hh, ws_u);
  lstm_kernel<<<64, 256, 0, stream>>>(inp, lengths, h0, c0, emb, b_ih, b_hh,
                                      ws_u, outh, outc);
  decode_kernel<<<BATCH, 64, 0, stream>>>(outh, dec_w, dec);
}